// Round 6
// baseline (176.251 us; speedup 1.0000x reference)
//
#include <hip/hip_runtime.h>

// Binary-weight dense: out[M,N] = scale * x[M,K] @ W[K,N], W = kernel ? +1 : -1
// M = 16384, K = 1024, N = 1024.
// R6: fuse the x fp32->bf16 conversion INTO the GEMM staging (convert_x pass
// eliminated: -1 dispatch, -32 MB net HBM). A is loaded as fp32 float4,
// converted in VGPRs, ds_write_b64'd into the XOR-swizzled bf16 LDS layout.
// W stays pre-converted ([n][k] bf16) and staged via global_load_lds w=16.
// Keeps R5's XCD-aware block swizzle (FETCH 133->34.5 MB win).
// Pipeline: detect_mode -> convert_w -> fused bf16_gemm.

#define M_TOT 16384
#define N_TOT 1024
#define K_TOT 1024

typedef __attribute__((ext_vector_type(8))) short bf16x8;
typedef __attribute__((ext_vector_type(4))) float f32x4;

__device__ __forceinline__ unsigned short f2bf(float f) {
    unsigned int u = __builtin_bit_cast(unsigned int, f);
    u += 0x7FFFu + ((u >> 16) & 1u);   // round-to-nearest-even
    return (unsigned short)(u >> 16);
}

// int32 bools -> all words 0/1; byte-packed bools -> some word >1 among the
// first 1024 words with overwhelming probability.
__global__ void detect_mode(const unsigned int* __restrict__ k32, int* __restrict__ flag) {
    __shared__ int s;
    if (threadIdx.x == 0) s = 0;
    __syncthreads();
    int bad = 0;
    for (int i = threadIdx.x; i < 1024; i += 256)
        if (k32[i] > 1u) bad = 1;
    if (bad) atomicOr(&s, 1);
    __syncthreads();
    if (threadIdx.x == 0) flag[0] = s;   // 1 = byte mode, 0 = int32 mode
}

// ---------------- prepass: W bools [k][n] -> +-1 bf16 [n][k] ----------------
__global__ __launch_bounds__(256) void convert_w(
    const void* __restrict__ w_raw, unsigned short* __restrict__ wt,
    const int* __restrict__ mode_p)
{
    __shared__ unsigned short tile[64 * 72];
    const int tid = threadIdx.x;
    const int k0 = (blockIdx.x & 15) * 64;
    const int n0 = (blockIdx.x >> 4) * 64;
    const int row = tid >> 2;            // k-local
    const int seg = (tid & 3) * 16;      // n-local group of 16

    if (mode_p[0] == 0) {
        const unsigned int* w = (const unsigned int*)w_raw;
        const uint4* src = reinterpret_cast<const uint4*>(
            w + (size_t)(k0 + row) * N_TOT + n0 + seg);
        #pragma unroll
        for (int q = 0; q < 4; ++q) {
            uint4 v = src[q];
            ushort4 h;
            h.x = v.x ? 0x3F80u : 0xBF80u;
            h.y = v.y ? 0x3F80u : 0xBF80u;
            h.z = v.z ? 0x3F80u : 0xBF80u;
            h.w = v.w ? 0x3F80u : 0xBF80u;
            *reinterpret_cast<ushort4*>(&tile[row * 72 + seg + q * 4]) = h;
        }
    } else {
        const unsigned char* w = (const unsigned char*)w_raw;
        uint4 v = *reinterpret_cast<const uint4*>(
            w + (size_t)(k0 + row) * N_TOT + n0 + seg);
        unsigned char b[16];
        *reinterpret_cast<uint4*>(b) = v;
        #pragma unroll
        for (int q = 0; q < 4; ++q) {
            ushort4 h;
            h.x = b[q * 4 + 0] ? 0x3F80u : 0xBF80u;
            h.y = b[q * 4 + 1] ? 0x3F80u : 0xBF80u;
            h.z = b[q * 4 + 2] ? 0x3F80u : 0xBF80u;
            h.w = b[q * 4 + 3] ? 0x3F80u : 0xBF80u;
            *reinterpret_cast<ushort4*>(&tile[row * 72 + seg + q * 4]) = h;
        }
    }
    __syncthreads();
    {   // write-out: thread -> (n, 16 consecutive k)
        int n = tid >> 2, kseg = (tid & 3) * 16;
        ushort4 o[4];
        #pragma unroll
        for (int j = 0; j < 16; ++j)
            ((unsigned short*)o)[j] = tile[(kseg + j) * 72 + n];
        ushort4* dst = reinterpret_cast<ushort4*>(wt + (size_t)(n0 + n) * K_TOT + k0 + kseg);
        dst[0] = o[0]; dst[1] = o[1]; dst[2] = o[2]; dst[3] = o[3];
    }
}

// ------- fused GEMM: out = scale * bf16(x) @ BT^T, x converted in staging -------
__global__ __launch_bounds__(256) void bf16_gemm(
    const float* __restrict__ X,             // [M][K] fp32
    const unsigned short* __restrict__ BT,   // [N][K] bf16 (pre-transposed W)
    const float* __restrict__ scale_p, float* __restrict__ out)
{
    // XOR-chunk-swizzled LDS: LDS[r] slot c holds global k-chunk c^(r&7).
    // (B requires it for bank balance under global_load_lds's uniform-base rule;
    //  A uses the same layout so fragment-read code is shared.)
    __shared__ unsigned short As[128 * 64];  // 16 KiB bf16 (post-conversion)
    __shared__ unsigned short Bs[128 * 64];

    const int tid  = threadIdx.x;
    const int lane = tid & 63;
    const int wave = tid >> 6;
    const int wm = (wave & 1) * 64;
    const int wn = (wave >> 1) * 64;

    // XCD-aware swizzle: the 8 blocks sharing an A m-strip keep blockIdx%8
    // invariant -> same XCD under round-robin -> one L2 fill per strip.
    const int j  = blockIdx.x & 7;
    const int s  = blockIdx.x >> 3;
    const int by = ((s >> 3) << 3) | j;   // 0..127
    const int bx = s & 7;                 // 0..7
    const int m0 = by * 128, n0 = bx * 128;

    const int fr = lane & 15, fq = lane >> 4;
    const float scale = scale_p[0];

    // B staging (global_load_lds): issue q of wave w covers LDS rows w*32+q*8..+8;
    // lane i -> row += i>>3, LDS chunk i&7; source global k-chunk = (i&7)^(i>>3).
    const int srow = wave * 32 + (lane >> 3);
    const int skch = (lane & 7) ^ (lane >> 3);

    // A staging (fp32 load + convert + ds_write_b64):
    // load q: row = q*16 + (tid>>4), k-seg = (tid&15)*4 fp32 (16 B, coalesced in
    // 256-B runs of 16 lanes). LDS slot: chunk c=(tid&15)>>1 swizzled, half tid&1.
    const int arow = tid >> 4;            // + q*16
    const int akseg = (tid & 15) * 4;
    const int achunk = (tid & 15) >> 1;
    const int ahalf = tid & 1;

    f32x4 acc[4][4] = {};

    for (int k0 = 0; k0 < K_TOT; k0 += 64) {
        // --- B first: async DMA overlaps A's conversion VALU ---
        #pragma unroll
        for (int q = 0; q < 4; ++q) {
            const unsigned short* g = BT + (size_t)(n0 + srow + q * 8) * K_TOT + k0 + skch * 8;
            __builtin_amdgcn_global_load_lds(
                (const __attribute__((address_space(1))) void*)g,
                (__attribute__((address_space(3))) void*)&Bs[wave * 2048 + q * 512],
                16, 0, 0);
        }
        // --- A: 8 float4 fp32 loads -> bf16 -> swizzled ds_write_b64 ---
        #pragma unroll
        for (int q = 0; q < 8; ++q) {
            const int row = q * 16 + arow;
            const float4 v = *reinterpret_cast<const float4*>(
                X + (size_t)(m0 + row) * K_TOT + k0 + akseg);
            ushort4 h;
            h.x = f2bf(v.x); h.y = f2bf(v.y); h.z = f2bf(v.z); h.w = f2bf(v.w);
            const int slot = achunk ^ (row & 7);
            *reinterpret_cast<ushort4*>(&As[row * 64 + slot * 8 + ahalf * 4]) = h;
        }
        __syncthreads();   // drains vmcnt (B DMA) + lgkmcnt (A ds_writes)

        #pragma unroll
        for (int ks = 0; ks < 2; ++ks) {
            bf16x8 af[4], bfr[4];
            #pragma unroll
            for (int mi = 0; mi < 4; ++mi) {
                int r  = wm + mi * 16 + fr;
                int ch = (ks * 4 + fq) ^ (r & 7);
                af[mi] = *reinterpret_cast<const bf16x8*>(&As[r * 64 + ch * 8]);
            }
            #pragma unroll
            for (int ni = 0; ni < 4; ++ni) {
                int r  = wn + ni * 16 + fr;
                int ch = (ks * 4 + fq) ^ (r & 7);
                bfr[ni] = *reinterpret_cast<const bf16x8*>(&Bs[r * 64 + ch * 8]);
            }
            #pragma unroll
            for (int mi = 0; mi < 4; ++mi)
                #pragma unroll
                for (int ni = 0; ni < 4; ++ni)
                    acc[mi][ni] = __builtin_amdgcn_mfma_f32_16x16x32_bf16(
                        af[mi], bfr[ni], acc[mi][ni], 0, 0, 0);
        }
        __syncthreads();
    }

    // epilogue: C/D layout col = fr, row = fq*4 + j  (m89/m91-verified)
    #pragma unroll
    for (int mi = 0; mi < 4; ++mi) {
        #pragma unroll
        for (int ni = 0; ni < 4; ++ni) {
            const int col  = n0 + wn + ni * 16 + fr;
            const int rowb = m0 + wm + mi * 16 + fq * 4;
            #pragma unroll
            for (int jj = 0; jj < 4; ++jj)
                out[(size_t)(rowb + jj) * N_TOT + col] = scale * acc[mi][ni][jj];
        }
    }
}

// ---------------- fallback (ws too small): fused kernel, int32 weights ----------------
#define BKP 40
__global__ __launch_bounds__(256, 2) void binary_dense_gemm(
    const float* __restrict__ x, const int* __restrict__ kern,
    const float* __restrict__ scale_p, float* __restrict__ out)
{
    __shared__ unsigned short Asf[128 * BKP];
    __shared__ unsigned short Bsf[128 * BKP];
    const int tid = threadIdx.x, lane = tid & 63, wave = tid >> 6;
    const int wm = (wave & 1) * 64, wn = (wave >> 1) * 64;
    const int bx = blockIdx.x & 7, by = blockIdx.x >> 3;
    const int m0 = by * 128, n0 = bx * 128;
    const float scale = scale_p[0];
    const int fr = lane & 15, fq = lane >> 4;
    f32x4 acc[4][4] = {};
    for (int k0 = 0; k0 < K_TOT; k0 += 32) {
        #pragma unroll
        for (int i = 0; i < 4; ++i) {
            int slot = tid + i * 256, row = slot >> 3, kg = (slot & 7) << 2;
            const float4 v = *reinterpret_cast<const float4*>(x + (size_t)(m0 + row) * K_TOT + k0 + kg);
            ushort4 h;
            h.x = f2bf(v.x); h.y = f2bf(v.y); h.z = f2bf(v.z); h.w = f2bf(v.w);
            *reinterpret_cast<ushort4*>(&Asf[row * BKP + kg]) = h;
        }
        #pragma unroll
        for (int i = 0; i < 4; ++i) {
            int slot = tid + i * 256, nl = slot & 127, kg = (slot >> 7) << 2;
            ushort4 h;
            h.x = kern[(size_t)(k0 + kg + 0) * N_TOT + n0 + nl] ? 0x3F80u : 0xBF80u;
            h.y = kern[(size_t)(k0 + kg + 1) * N_TOT + n0 + nl] ? 0x3F80u : 0xBF80u;
            h.z = kern[(size_t)(k0 + kg + 2) * N_TOT + n0 + nl] ? 0x3F80u : 0xBF80u;
            h.w = kern[(size_t)(k0 + kg + 3) * N_TOT + n0 + nl] ? 0x3F80u : 0xBF80u;
            *reinterpret_cast<ushort4*>(&Bsf[nl * BKP + kg]) = h;
        }
        __syncthreads();
        bf16x8 af[4], bfr[4];
        #pragma unroll
        for (int mi = 0; mi < 4; ++mi)
            af[mi] = *reinterpret_cast<const bf16x8*>(&Asf[(wm + mi * 16 + fr) * BKP + fq * 8]);
        #pragma unroll
        for (int ni = 0; ni < 4; ++ni)
            bfr[ni] = *reinterpret_cast<const bf16x8*>(&Bsf[(wn + ni * 16 + fr) * BKP + fq * 8]);
        #pragma unroll
        for (int mi = 0; mi < 4; ++mi)
            #pragma unroll
            for (int ni = 0; ni < 4; ++ni)
                acc[mi][ni] = __builtin_amdgcn_mfma_f32_16x16x32_bf16(af[mi], bfr[ni], acc[mi][ni], 0, 0, 0);
        __syncthreads();
    }
    #pragma unroll
    for (int mi = 0; mi < 4; ++mi)
        #pragma unroll
        for (int ni = 0; ni < 4; ++ni) {
            const int col = n0 + wn + ni * 16 + fr;
            const int rowb = m0 + wm + mi * 16 + fq * 4;
            #pragma unroll
            for (int jj = 0; jj < 4; ++jj)
                out[(size_t)(rowb + jj) * N_TOT + col] = scale * acc[mi][ni][jj];
        }
}

extern "C" void kernel_launch(void* const* d_in, const int* in_sizes, int n_in,
                              void* d_out, int out_size, void* d_ws, size_t ws_size,
                              hipStream_t stream) {
    const float* x     = (const float*)d_in[0];
    const void*  kern  = d_in[1];
    const float* scale = (const float*)d_in[2];
    float*       out   = (float*)d_out;

    const size_t wt_bytes = (size_t)N_TOT * K_TOT * 2;           // 2 MiB
    const size_t flag_off = 256;                                  // keep wt 16B-aligned
    if (ws_size >= flag_off + wt_bytes) {
        int*            flag = (int*)d_ws;
        unsigned short* wt   = (unsigned short*)((char*)d_ws + flag_off);
        hipLaunchKernelGGL(detect_mode, dim3(1), dim3(256), 0, stream,
                           (const unsigned int*)kern, flag);
        hipLaunchKernelGGL(convert_w, dim3(256), dim3(256), 0, stream, kern, wt, flag);
        hipLaunchKernelGGL(bf16_gemm, dim3(1024), dim3(256), 0, stream,
                           x, wt, scale, out);
    } else {
        hipLaunchKernelGGL(binary_dense_gemm, dim3(1024), dim3(256), 0, stream,
                           x, (const int*)kern, scale, out);
    }
}